// Round 5
// baseline (99.564 us; speedup 1.0000x reference)
//
#include <hip/hip_runtime.h>
#include <math.h>

#define DDIM  200
#define D4    (DDIM / 4)   // 50
#define CCH   50
#define NREL  237
#define MAXE  20           // max elements per chunk/block
#define MAXR  (2 * MAXE)   // max rows (src+tail interleaved) = 40
#define NT    256
#define NWAVE 4
#define SLOTS (MAXR / NWAVE)          // 10 row-slots per wave
#define TPW   ((CCH * D4) / NWAVE)    // 625 epilogue tasks per wave

// ---------- Kernel 1: counting sort by relation + balanced chunk emission ----------
__global__ __launch_bounds__(1024) void relsort_kernel(
    const int* __restrict__ bi, int B, int nblk,
    int* __restrict__ perm, int* __restrict__ blk_r,
    int* __restrict__ blk_start, int* __restrict__ blk_cnt)
{
    __shared__ int hist[NREL];
    __shared__ int offs[NREL];
    __shared__ int wsum[16], wsum2[16];
    const int tid  = threadIdx.x;
    const int lane = tid & 63;
    const int w    = tid >> 6;

    if (tid < NREL) hist[tid] = 0;
    __syncthreads();
    for (int i = tid; i < B; i += 1024)
        atomicAdd(&hist[bi[i * 3 + 1]], 1);
    __syncthreads();

    // wave-parallel exclusive scans of hist and nchunks=ceil(hist/MAXE)
    const int v  = (tid < NREL) ? hist[tid] : 0;
    const int v2 = (tid < NREL) ? (v + MAXE - 1) / MAXE : 0;
    int s = v, s2 = v2;
    #pragma unroll
    for (int off = 1; off < 64; off <<= 1) {
        const int u  = __shfl_up(s,  off, 64);
        const int u2 = __shfl_up(s2, off, 64);
        if (lane >= off) { s += u; s2 += u2; }
    }
    if (lane == 63) { wsum[w] = s; wsum2[w] = s2; }
    __syncthreads();
    int base = 0, base2 = 0;
    for (int i = 0; i < w; ++i) { base += wsum[i]; base2 += wsum2[i]; }
    const int my_off  = base  + s  - v;    // exclusive prefix of hist
    const int my_boff = base2 + s2 - v2;   // exclusive prefix of nchunks
    if (tid < NREL) offs[tid] = my_off;
    __syncthreads();

    // zero all block slots (d_ws is poisoned), then emit balanced chunks
    for (int i = tid; i < nblk; i += 1024) blk_cnt[i] = 0;
    if (tid < NREL && v > 0) {
        const int nb = (v + MAXE - 1) / MAXE;
        const int cb = v / nb, ext = v - cb * nb;   // chunk sizes cb+1 (ext) / cb
        int pos = my_off;
        for (int j = 0; j < nb; ++j) {
            const int c = cb + (j < ext ? 1 : 0);
            blk_r[my_boff + j]     = tid;
            blk_start[my_boff + j] = pos;
            blk_cnt[my_boff + j]   = c;
            pos += c;
        }
    }
    __syncthreads();   // emission reads offs before scatter mutates it
    for (int i = tid; i < B; i += 1024) {
        const int pos = atomicAdd(&offs[bi[i * 3 + 1]], 1);
        perm[pos] = i;
    }
}

// ---------- Kernel 2: one block per chunk; register-tiled dual matvec + fused tail ----------
__global__ __launch_bounds__(NT) void spkbgat_main_kernel(
    const int*   __restrict__ bi,
    const float* __restrict__ ent,
    const float* __restrict__ rel_emb,
    const float* __restrict__ W,
    const float* __restrict__ conv_w,
    const float* __restrict__ conv_b,
    const float* __restrict__ fc_w,
    const float* __restrict__ fc_b,
    const int*   __restrict__ perm,
    const int*   __restrict__ blk_r,
    const int*   __restrict__ blk_start,
    const int*   __restrict__ blk_cnt,
    int nblk,
    float*       __restrict__ out)
{
    // Xsh: staged src/tail rows (row 2e = src_e, 2e+1 = tail_e) pre-matvec;
    //      overwritten in-place with tanh'd se/te post-matvec (disjoint rows per wave).
    __shared__ __align__(16) float  Xsh[MAXR][DDIM];   // 32 KB
    __shared__ __align__(16) float4 rl4[D4];
    __shared__ __align__(16) float  cwb[CCH][4];       // {w0,w1,w2,b}
    __shared__ float red[NWAVE][MAXE];

    const int tid  = threadIdx.x;
    const int w    = tid >> 6;
    const int lane = tid & 63;

    // bijective XCD-chunked swizzle: consecutive sorted chunks -> same XCD L2
    const int bid = blockIdx.x;
    const int q = nblk >> 3, rmd = nblk & 7;
    const int xcd = bid & 7, idx = bid >> 3;
    const int gidx = (xcd < rmd ? xcd * (q + 1) : rmd * (q + 1) + (xcd - rmd) * q) + idx;

    const int cnt = blk_cnt[gidx];
    if (cnt == 0) return;   // block-uniform: safe before barriers

    const int r     = blk_r[gidx];
    const int start = blk_start[gidx];
    const int rows  = 2 * cnt;

    // ---- stage: conv weights, rel vector, X rows (coalesced float4) ----
    if (tid < CCH) {
        cwb[tid][0] = conv_w[tid * 3 + 0];
        cwb[tid][1] = conv_w[tid * 3 + 1];
        cwb[tid][2] = conv_w[tid * 3 + 2];
        cwb[tid][3] = conv_b[tid];
    }
    if (tid < D4) rl4[tid] = ((const float4*)rel_emb)[r * D4 + tid];
    for (int i = tid; i < rows * D4; i += NT) {
        const int row = i / D4, d4 = i - row * D4;
        const int b   = perm[start + (row >> 1)];
        const int eid = bi[b * 3 + ((row & 1) ? 2 : 0)];
        *(float4*)&Xsh[row][4 * d4] =
            ((const float4*)ent)[(size_t)eid * D4 + d4];
    }
    __syncthreads();

    // ---- matvec: wave w owns rows {w, w+4, ...}; lane c<50 owns cols 4c..4c+3 ----
    if (lane < D4) {
        const float4* __restrict__ wp = (const float4*)(W + (size_t)r * (DDIM * DDIM));
        float4 acc[SLOTS];
        #pragma unroll
        for (int s = 0; s < SLOTS; ++s) acc[s] = float4{0.f, 0.f, 0.f, 0.f};

        for (int d4 = 0; d4 < D4; ++d4) {
            const float4 wv0 = wp[(4 * d4 + 0) * D4 + lane];
            const float4 wv1 = wp[(4 * d4 + 1) * D4 + lane];
            const float4 wv2 = wp[(4 * d4 + 2) * D4 + lane];
            const float4 wv3 = wp[(4 * d4 + 3) * D4 + lane];
            #pragma unroll
            for (int s = 0; s < SLOTS; ++s) {
                const int row = NWAVE * s + w;
                if (row < rows) {
                    const float4 x4 = *(const float4*)&Xsh[row][4 * d4]; // broadcast b128
                    acc[s].x = fmaf(x4.x, wv0.x, acc[s].x);
                    acc[s].y = fmaf(x4.x, wv0.y, acc[s].y);
                    acc[s].z = fmaf(x4.x, wv0.z, acc[s].z);
                    acc[s].w = fmaf(x4.x, wv0.w, acc[s].w);
                    acc[s].x = fmaf(x4.y, wv1.x, acc[s].x);
                    acc[s].y = fmaf(x4.y, wv1.y, acc[s].y);
                    acc[s].z = fmaf(x4.y, wv1.z, acc[s].z);
                    acc[s].w = fmaf(x4.y, wv1.w, acc[s].w);
                    acc[s].x = fmaf(x4.z, wv2.x, acc[s].x);
                    acc[s].y = fmaf(x4.z, wv2.y, acc[s].y);
                    acc[s].z = fmaf(x4.z, wv2.z, acc[s].z);
                    acc[s].w = fmaf(x4.z, wv2.w, acc[s].w);
                    acc[s].x = fmaf(x4.w, wv3.x, acc[s].x);
                    acc[s].y = fmaf(x4.w, wv3.y, acc[s].y);
                    acc[s].z = fmaf(x4.w, wv3.z, acc[s].z);
                    acc[s].w = fmaf(x4.w, wv3.w, acc[s].w);
                }
            }
        }
        // tanh + in-place writeback (wave-private rows -> no barrier needed here)
        #pragma unroll
        for (int s = 0; s < SLOTS; ++s) {
            const int row = NWAVE * s + w;
            if (row < rows) {
                const float4 v = {tanhf(acc[s].x), tanhf(acc[s].y),
                                  tanhf(acc[s].z), tanhf(acc[s].w)};
                *(float4*)&Xsh[row][4 * lane] = v;   // contiguous, conflict-free
            }
        }
    }
    __syncthreads();

    // ---- fused conv+relu+fc: fc/conv weights in regs, reused over all elements ----
    float sum[MAXE];
    #pragma unroll
    for (int e = 0; e < MAXE; ++e) sum[e] = 0.f;

    for (int t = w * TPW + lane; t < (w + 1) * TPW; t += 64) {
        const int c  = t / D4;
        const int d4 = t - c * D4;
        const int d  = 4 * d4;
        const float4 cw = *(const float4*)&cwb[c][0];
        const float4 rv = rl4[d4];
        const float4 fv = ((const float4*)fc_w)[c * D4 + d4];
        #pragma unroll
        for (int e = 0; e < MAXE; ++e) {
            if (e < cnt) {   // block-uniform predicate, static acc index
                const float4 sv = *(const float4*)&Xsh[2 * e][d];
                const float4 tv = *(const float4*)&Xsh[2 * e + 1][d];
                const float v0 = fmaf(cw.x, sv.x, fmaf(cw.y, rv.x, fmaf(cw.z, tv.x, cw.w)));
                const float v1 = fmaf(cw.x, sv.y, fmaf(cw.y, rv.y, fmaf(cw.z, tv.y, cw.w)));
                const float v2 = fmaf(cw.x, sv.z, fmaf(cw.y, rv.z, fmaf(cw.z, tv.z, cw.w)));
                const float v3 = fmaf(cw.x, sv.w, fmaf(cw.y, rv.w, fmaf(cw.z, tv.w, cw.w)));
                sum[e] = fmaf(fmaxf(v0, 0.f), fv.x, sum[e]);
                sum[e] = fmaf(fmaxf(v1, 0.f), fv.y, sum[e]);
                sum[e] = fmaf(fmaxf(v2, 0.f), fv.z, sum[e]);
                sum[e] = fmaf(fmaxf(v3, 0.f), fv.w, sum[e]);
            }
        }
    }
    #pragma unroll
    for (int e = 0; e < MAXE; ++e) {
        if (e < cnt) {
            #pragma unroll
            for (int off = 32; off; off >>= 1)
                sum[e] += __shfl_down(sum[e], off, 64);
            if (lane == 0) red[w][e] = sum[e];
        }
    }
    __syncthreads();
    if (tid < cnt) {
        const int b = perm[start + tid];
        out[b] = red[0][tid] + red[1][tid] + red[2][tid] + red[3][tid] + fc_b[0];
    }
}

extern "C" void kernel_launch(void* const* d_in, const int* in_sizes, int n_in,
                              void* d_out, int out_size, void* d_ws, size_t ws_size,
                              hipStream_t stream) {
    const int*   bi      = (const int*)  d_in[0];
    const float* ent     = (const float*)d_in[1];
    const float* rel_emb = (const float*)d_in[2];
    const float* W       = (const float*)d_in[3];
    const float* conv_w  = (const float*)d_in[4];
    const float* conv_b  = (const float*)d_in[5];
    const float* fc_w    = (const float*)d_in[6];
    const float* fc_b    = (const float*)d_in[7];
    float*       out     = (float*)d_out;

    const int B    = in_sizes[0] / 3;                      // 8192
    const int nblk = NREL + (B + MAXE - 1) / MAXE;         // worst-case chunks

    int* perm      = (int*)d_ws;
    int* blk_r     = perm + B;
    int* blk_start = blk_r + nblk;
    int* blk_cnt   = blk_start + nblk;

    relsort_kernel<<<1, 1024, 0, stream>>>(bi, B, nblk, perm, blk_r, blk_start, blk_cnt);
    spkbgat_main_kernel<<<nblk, NT, 0, stream>>>(
        bi, ent, rel_emb, W, conv_w, conv_b, fc_w, fc_b,
        perm, blk_r, blk_start, blk_cnt, nblk, out);
}